// Round 3
// baseline (464.190 us; speedup 1.0000x reference)
//
#include <hip/hip_runtime.h>

typedef unsigned short u16;
typedef unsigned int u32;
typedef __bf16 bf16x8 __attribute__((ext_vector_type(8)));
typedef float floatx4 __attribute__((ext_vector_type(4)));
typedef u16 u16x4 __attribute__((ext_vector_type(4)));
typedef u16 u16x8 __attribute__((ext_vector_type(8)));
typedef u32 u32x2 __attribute__((ext_vector_type(2)));

#define B_ 4
#define T_ 1024
#define C_ 2048
#define H_ 32
#define HD_ 64

__device__ __forceinline__ float b2f(u16 u) {
    u32 x = ((u32)u) << 16;
    return __builtin_bit_cast(float, x);
}
__device__ __forceinline__ u16 f2b(float f) {          // RNE (epilogues)
    u32 i = __builtin_bit_cast(u32, f);
    u32 r = (i + 0x7FFFu + ((i >> 16) & 1u)) >> 16;
    return (u16)r;
}
// pack two fp32 -> two bf16 (round-half-up), 2 adds + 1 v_perm_b32
__device__ __forceinline__ u32 pack2(float a, float b) {
    const u32 ua = __builtin_bit_cast(u32, a) + 0x8000u;
    const u32 ub = __builtin_bit_cast(u32, b) + 0x8000u;
    return __builtin_amdgcn_perm(ub, ua, 0x07060302u);  // [ub_hi : ua_hi]
}

#define GLOAD16(gp, lp) __builtin_amdgcn_global_load_lds( \
    (const __attribute__((address_space(1))) void*)(gp),  \
    (__attribute__((address_space(3))) void*)(lp), 16, 0, 0)

#define BAR()   __builtin_amdgcn_s_barrier()
#define LGKM0() asm volatile("s_waitcnt lgkmcnt(0)" ::: "memory")
#define VMW(n)  asm volatile("s_waitcnt vmcnt(" #n ")" ::: "memory")
#define PRIO1() __builtin_amdgcn_s_setprio(1)
#define PRIO0() __builtin_amdgcn_s_setprio(0)
#define MFMA(a, b, c) __builtin_amdgcn_mfma_f32_16x16x32_bf16(a, b, c, 0, 0, 0)

// ---------------------------------------------------------------------------
// fp32 -> bf16 elementwise convert (HBM-bound prework)
// ---------------------------------------------------------------------------
__global__ __launch_bounds__(256) void convert_bf16(const float* __restrict__ src,
                                                    u16* __restrict__ dst, int n4) {
    const int stride = gridDim.x * 256;
    for (int i = blockIdx.x * 256 + threadIdx.x; i < n4; i += stride) {
        const floatx4 v = *(const floatx4*)(src + (size_t)i * 4);
        const u32x2 h = {pack2(v.x, v.y), pack2(v.z, v.w)};
        *(u32x2*)(dst + (size_t)i * 4) = h;
    }
}

// ---------------------------------------------------------------------------
// 256x256 8-phase GEMM for the QKV projection (T2+T3+T4+T5).
// 512 thr = 8 waves (2M x 4N), per-wave 128x64 output, BK=64, LDS 128KB
// (2 dbuf x (A 32KB + B 32KB)). Per K-tile 4 phases: Q0(12 ds_reads),
// Q1(4), Q2(8), Q3(0), each ending in a 16-MFMA setprio cluster. Staging of
// tile t+2 into the SAME buffer is placed one barrier after each region's
// last read: ph2 stages A-units{0,2} (read ph1), ph3 stages B{0,1} (read
// ph1+2), ph4 stages B{2,3}+A{1,3} (read ph2/ph3). vmcnt(8) at phases 4 and
// 8 only: leaves this K-tile's 8 prefetch instrs in flight, drains the tile
// needed by the NEXT 4 phases. Builtin s_barrier (no implicit vmcnt(0)
// drain, per m201 template). Bank swizzle identical to the verified 128^2
// kernel (0 conflicts): staging lane fetches global col-block s^(row&7) into
// slot s; reads XOR with row&7.
// Epilogue: bias + RoPE + q/k/v scatter, byte-identical math to prior rounds.
// ---------------------------------------------------------------------------
#define HALFSTEP(BUF, STG, TS, VMN)                                           \
  {                                                                           \
    const u16* as = &As[BUF][0];                                              \
    const u16* bs = &Bs[BUF][0];                                              \
    u16* asw = &As[BUF][0];                                                   \
    u16* bsw = &Bs[BUF][0];                                                   \
    const u16* Apt = Abase + (size_t)(TS) * 64;                               \
    const u16* Wpt = Wbase + (size_t)(TS) * 64;                               \
    bf16x8 afr[4][2], bfr[4][2];                                              \
    /* ---- ph1: Q0 (reads af[0..3], bf[0..1]) ---- */                        \
    _Pragma("unroll") for (int i = 0; i < 4; i++) {                           \
      afr[i][0] = *(const bf16x8*)&as[aro + i * 1024 + co0];                  \
      afr[i][1] = *(const bf16x8*)&as[aro + i * 1024 + co1];                  \
    }                                                                         \
    _Pragma("unroll") for (int j = 0; j < 2; j++) {                           \
      bfr[j][0] = *(const bf16x8*)&bs[bro + j * 1024 + co0];                  \
      bfr[j][1] = *(const bf16x8*)&bs[bro + j * 1024 + co1];                  \
    }                                                                         \
    BAR(); LGKM0(); PRIO1();                                                  \
    _Pragma("unroll") for (int i = 0; i < 4; i++)                             \
      _Pragma("unroll") for (int j = 0; j < 2; j++) {                         \
        acc[i][j] = MFMA(afr[i][0], bfr[j][0], acc[i][j]);                    \
        acc[i][j] = MFMA(afr[i][1], bfr[j][1], acc[i][j]);                    \
      }                                                                       \
    PRIO0(); BAR();                                                           \
    /* ---- ph2: Q1 (reads bf[2..3]); stage A u0,u2 of TS ---- */             \
    _Pragma("unroll") for (int j = 2; j < 4; j++) {                           \
      bfr[j][0] = *(const bf16x8*)&bs[bro + j * 1024 + co0];                  \
      bfr[j][1] = *(const bf16x8*)&bs[bro + j * 1024 + co1];                  \
    }                                                                         \
    if (STG) {                                                                \
      GLOAD16(Apt, &asw[(w * 8) * 64]);                                       \
      GLOAD16(Apt + (size_t)2 * 131072, &asw[(128 + w * 8) * 64]);            \
    }                                                                         \
    BAR(); LGKM0(); PRIO1();                                                  \
    _Pragma("unroll") for (int i = 0; i < 4; i++)                             \
      _Pragma("unroll") for (int j = 2; j < 4; j++) {                         \
        acc[i][j] = MFMA(afr[i][0], bfr[j][0], acc[i][j]);                    \
        acc[i][j] = MFMA(afr[i][1], bfr[j][1], acc[i][j]);                    \
      }                                                                       \
    PRIO0(); BAR();                                                           \
    /* ---- ph3: Q2 (reads af[4..7]); stage B u0,u1 ---- */                   \
    _Pragma("unroll") for (int i = 0; i < 4; i++) {                           \
      afr[i][0] = *(const bf16x8*)&as[aro + 4096 + i * 1024 + co0];           \
      afr[i][1] = *(const bf16x8*)&as[aro + 4096 + i * 1024 + co1];           \
    }                                                                         \
    if (STG) {                                                                \
      GLOAD16(Wpt, &bsw[(w * 8) * 64]);                                       \
      GLOAD16(Wpt + (size_t)131072, &bsw[(64 + w * 8) * 64]);                 \
    }                                                                         \
    BAR(); LGKM0(); PRIO1();                                                  \
    _Pragma("unroll") for (int i = 0; i < 4; i++)                             \
      _Pragma("unroll") for (int j = 0; j < 2; j++) {                         \
        acc[4 + i][j] = MFMA(afr[i][0], bfr[j][0], acc[4 + i][j]);            \
        acc[4 + i][j] = MFMA(afr[i][1], bfr[j][1], acc[4 + i][j]);            \
      }                                                                       \
    PRIO0(); BAR();                                                           \
    /* ---- ph4: Q3 (no reads); stage B u2,u3 + A u1,u3; vmcnt ---- */        \
    if (STG) {                                                                \
      GLOAD16(Wpt + (size_t)2 * 131072, &bsw[(128 + w * 8) * 64]);            \
      GLOAD16(Wpt + (size_t)3 * 131072, &bsw[(192 + w * 8) * 64]);            \
      GLOAD16(Apt + (size_t)131072, &asw[(64 + w * 8) * 64]);                 \
      GLOAD16(Apt + (size_t)3 * 131072, &asw[(192 + w * 8) * 64]);            \
    }                                                                         \
    BAR(); PRIO1();                                                           \
    _Pragma("unroll") for (int i = 0; i < 4; i++)                             \
      _Pragma("unroll") for (int j = 2; j < 4; j++) {                         \
        acc[4 + i][j] = MFMA(afr[i][0], bfr[j][0], acc[4 + i][j]);            \
        acc[4 + i][j] = MFMA(afr[i][1], bfr[j][1], acc[4 + i][j]);            \
      }                                                                       \
    PRIO0(); VMW(VMN); BAR();                                                 \
  }

__global__ __launch_bounds__(512) void gemm256_qkv(const u16* __restrict__ A,
                                                   const u16* __restrict__ W,
                                                   const float* __restrict__ bias,
                                                   const float* __restrict__ rope,
                                                   u16* __restrict__ oq,
                                                   u16* __restrict__ ok,
                                                   u16* __restrict__ ov) {
    __shared__ __align__(16) u16 As[2][256 * 64];
    __shared__ __align__(16) u16 Bs[2][256 * 64];

    const int tid = threadIdx.x;
    const int w = tid >> 6, lane = tid & 63;
    const int quad = lane >> 4, l15 = lane & 15;
    const int wr = w >> 2, wc = w & 3;

    // XCD swizzle: 384 blocks, 48/XCD, column-grouped (3 bx x 16 by per XCD)
    // -> each XCD's W working set = 3 panels = 3MB, fits its 4MB L2.
    const int lin = blockIdx.y * 24 + blockIdx.x;
    const int swz = (lin & 7) * 48 + (lin >> 3);
    const int mBase = (swz & 15) * 256;
    const int nBase = (swz >> 4) * 256;

    // staging source: row srow within unit, pre-swizzled col slot
    const int srow = w * 8 + (lane >> 3);
    const int scol = ((lane & 7) ^ (lane >> 3)) * 8;
    const u16* Abase = A + (size_t)(mBase + srow) * 2048 + scol;
    const u16* Wbase = W + (size_t)(nBase + srow) * 2048 + scol;

    const int xk = l15 & 7;
    const int co0 = ((0 * 4 + quad) ^ xk) * 8;
    const int co1 = ((1 * 4 + quad) ^ xk) * 8;
    const int aro = (wr * 128 + l15) * 64;
    const int bro = (wc * 64 + l15) * 64;

    floatx4 acc[8][4] = {};

    // prologue: stage tiles 0 (buf0) and 1 (buf1); drain tile0, keep tile1 in flight
#pragma unroll
    for (int u = 0; u < 4; u++) {
        GLOAD16(Abase + (size_t)u * 131072, &As[0][(u * 64 + w * 8) * 64]);
        GLOAD16(Wbase + (size_t)u * 131072, &Bs[0][(u * 64 + w * 8) * 64]);
    }
#pragma unroll
    for (int u = 0; u < 4; u++) {
        GLOAD16(Abase + (size_t)u * 131072 + 64, &As[1][(u * 64 + w * 8) * 64]);
        GLOAD16(Wbase + (size_t)u * 131072 + 64, &Bs[1][(u * 64 + w * 8) * 64]);
    }
    VMW(8);
    BAR();

#pragma unroll 1
    for (int t = 0; t < 30; t += 2) {
        HALFSTEP(0, 1, t + 2, 8)
        HALFSTEP(1, 1, t + 3, 8)
    }
    // epilogue: tiles 30, 31 — no staging; vmcnt(0) drains tile31 before use
    HALFSTEP(0, 0, 0, 0)
    HALFSTEP(1, 0, 0, 0)

    // ---- epilogue: bias + RoPE + q/k/v scatter ----
    const int nq = nBase + wc * 64;
    float bv[4];
#pragma unroll
    for (int j = 0; j < 4; j++) bv[j] = bias[nq + j * 16 + l15];
    const int region = nq >> 11;            // 0=q 1=k 2=v (64-col range never straddles)
    const int hh = (nq & 2047) >> 6;
    const int d = l15;
    u16* dst = (region == 0) ? oq : ((region == 1) ? ok : ov);
#pragma unroll
    for (int mi = 0; mi < 8; mi++) {
#pragma unroll
        for (int r = 0; r < 4; r++) {
            const int m = mBase + wr * 128 + mi * 16 + quad * 4 + r;
            const int bb = m >> 10, tt = m & 1023;
            float v0 = acc[mi][0][r] + bv[0];
            float v1 = acc[mi][1][r] + bv[1];
            float v2 = acc[mi][2][r] + bv[2];
            float v3 = acc[mi][3][r] + bv[3];
            const size_t base = ((size_t)(bb * H_ + hh) * T_ + tt) * HD_;
            if (region < 2) {
                const float cz = rope[tt * 32 + d * 2];
                const float sz = rope[tt * 32 + d * 2 + 1];
                const float n0 = v0 * cz - v1 * sz;
                const float n1 = v1 * cz + v0 * sz;
                dst[base + d] = f2b(n0);
                dst[base + 16 + d] = f2b(n1);
            } else {
                dst[base + d] = f2b(v0);
                dst[base + 16 + d] = f2b(v1);
            }
            dst[base + 32 + d] = f2b(v2);
            dst[base + 48 + d] = f2b(v3);
        }
    }
}

// ---------------------------------------------------------------------------
// 128^2 m97-structure GEMM, kept for the output projection (N=2048: a 256^2
// grid would be 128 blocks = half the CUs idle; 512 blocks at 2/CU wins).
// MODE 1: epilogue bias, fp32 row-major store.
// ---------------------------------------------------------------------------
template <int MODE>
__global__ __launch_bounds__(256) void gemm_bt(const u16* __restrict__ A,
                                               const u16* __restrict__ W,
                                               const float* __restrict__ bias,
                                               const float* __restrict__ rope,
                                               void* __restrict__ o0v,
                                               u16* __restrict__ o1,
                                               u16* __restrict__ o2) {
    const int Kdim = 2048;
    __shared__ __align__(16) u16 As[128 * 64];
    __shared__ __align__(16) u16 Bs[128 * 64];

    const int tid = threadIdx.x;
    const int w = tid >> 6, lane = tid & 63;
    const int wr = w >> 1, wc = w & 1;
    const int quad = lane >> 4, l15 = lane & 15;
    const int mBase = blockIdx.y * 128, nBase = blockIdx.x * 128;

    floatx4 acc[4][4] = {};

    const int lrow = lane >> 3;
    const int lcol = ((lane & 7) ^ lrow) * 8;
    const u16* Ap = A + (size_t)(mBase + lrow) * Kdim + lcol;
    const u16* Wp = W + (size_t)(nBase + lrow) * Kdim + lcol;

    const int xk = l15 & 7;

    for (int k0 = 0; k0 < Kdim; k0 += 64) {
#pragma unroll
        for (int i = 0; i < 4; i++) {
            const int c = i * 4 + w;
            GLOAD16(Ap + (size_t)c * 8 * Kdim + k0, &As[c * 512]);
            GLOAD16(Wp + (size_t)c * 8 * Kdim + k0, &Bs[c * 512]);
        }
        __syncthreads();
#pragma unroll
        for (int ks = 0; ks < 64; ks += 32) {
            bf16x8 af[4], bfr[4];
#pragma unroll
            for (int i = 0; i < 4; i++) {
                const int co = (((ks >> 3) + quad) ^ xk) * 8;
                af[i] = *(const bf16x8*)&As[(wr * 64 + i * 16 + l15) * 64 + co];
            }
#pragma unroll
            for (int j = 0; j < 4; j++) {
                const int co = (((ks >> 3) + quad) ^ xk) * 8;
                bfr[j] = *(const bf16x8*)&Bs[(wc * 64 + j * 16 + l15) * 64 + co];
            }
#pragma unroll
            for (int i = 0; i < 4; i++)
#pragma unroll
                for (int j = 0; j < 4; j++)
                    acc[i][j] = __builtin_amdgcn_mfma_f32_16x16x32_bf16(af[i], bfr[j], acc[i][j], 0, 0, 0);
        }
        __syncthreads();
    }

    const int nq = nBase + wc * 64;
    float bv[4];
#pragma unroll
    for (int j = 0; j < 4; j++) bv[j] = bias[nq + j * 16 + l15];

    if (MODE == 0) {
        const int region = nq >> 11;
        const int h = (nq & 2047) >> 6;
        const int d = l15;
        u16* dst = (region == 0) ? (u16*)o0v : ((region == 1) ? o1 : o2);
#pragma unroll
        for (int i = 0; i < 4; i++) {
#pragma unroll
            for (int r = 0; r < 4; r++) {
                const int m = mBase + wr * 64 + i * 16 + quad * 4 + r;
                const int b = m >> 10, t = m & 1023;
                float v0 = acc[i][0][r] + bv[0];
                float v1 = acc[i][1][r] + bv[1];
                float v2 = acc[i][2][r] + bv[2];
                float v3 = acc[i][3][r] + bv[3];
                const size_t base = ((size_t)(b * H_ + h) * T_ + t) * HD_;
                if (region < 2) {
                    const float cz = rope[t * 32 + d * 2];
                    const float sz = rope[t * 32 + d * 2 + 1];
                    const float n0 = v0 * cz - v1 * sz;
                    const float n1 = v1 * cz + v0 * sz;
                    dst[base + d] = f2b(n0);
                    dst[base + 16 + d] = f2b(n1);
                } else {
                    dst[base + d] = f2b(v0);
                    dst[base + 16 + d] = f2b(v1);
                }
                dst[base + 32 + d] = f2b(v2);
                dst[base + 48 + d] = f2b(v3);
            }
        }
    } else {
        float* outf = (float*)o0v;
#pragma unroll
        for (int i = 0; i < 4; i++)
#pragma unroll
            for (int r = 0; r < 4; r++) {
                const int m = mBase + wr * 64 + i * 16 + quad * 4 + r;
                const size_t o = (size_t)m * 2048 + nq;
#pragma unroll
                for (int j = 0; j < 4; j++)
                    outf[o + j * 16 + l15] = acc[i][j][r] + bv[j];
            }
    }
}

// ---------------------------------------------------------------------------
// MFMA flash attention (balanced-pair version, verified round 1).
// ---------------------------------------------------------------------------
#define VT_STR 72

__global__ __launch_bounds__(256) void attn_mfma(const u16* __restrict__ qT,
                                                 const u16* __restrict__ kT,
                                                 const u16* __restrict__ vT,
                                                 u16* __restrict__ ctx) {
    __shared__ __align__(16) u16 Vt[2][64 * VT_STR];     // V^T: [hd][key], x2
    __shared__ __align__(16) u16 Pt[4 * 16 * VT_STR];    // per-wave P^T: [q][key]

    const int tid = threadIdx.x;
    const int w = tid >> 6, lane = tid & 63;
    const int quad = lane >> 4, l15 = lane & 15;
    const int bh = blockIdx.y;
    const size_t headBase = (size_t)bh * (T_ * HD_);

    u16* myPt = &Pt[w * 16 * VT_STR];
    const int vhd = tid & 63, vkb = tid >> 6;
    const float SC = 0.18033688011112042f;   // 0.125 * log2(e)

    int gb = 0;                              // Vt buffer parity (global across tiles)
#pragma unroll 1
    for (int ti = 0; ti < 2; ti++) {
        const int qt = ti ? (15 - (int)blockIdx.x) : (int)blockIdx.x;

        bf16x8 qf[2];
        {
            const u16* qrow = qT + headBase + ((size_t)qt * 64 + w * 16 + l15) * HD_ + quad * 8;
            qf[0] = __builtin_bit_cast(bf16x8, *(const u16x8*)(qrow));
            qf[1] = __builtin_bit_cast(bf16x8, *(const u16x8*)(qrow + 32));
        }

        float m_i = -1e30f, l_i = 0.f;
        floatx4 oacc[4] = {};

        for (int kt = 0; kt <= qt; kt++) {
            const u16* kp = kT + headBase + (size_t)kt * 64 * HD_;
            const u16* vp = vT + headBase + (size_t)kt * 64 * HD_;

            u16 vreg[16];
#pragma unroll
            for (int c = 0; c < 16; c++)
                vreg[c] = vp[(vkb * 16 + c) * HD_ + vhd];

            floatx4 st[4] = {};
#pragma unroll
            for (int mi = 0; mi < 4; mi++) {
                const u16* krow = kp + (mi * 16 + l15) * HD_ + quad * 8;
                const bf16x8 kf0 = __builtin_bit_cast(bf16x8, *(const u16x8*)(krow));
                const bf16x8 kf1 = __builtin_bit_cast(bf16x8, *(const u16x8*)(krow + 32));
                st[mi] = __builtin_amdgcn_mfma_f32_16x16x32_bf16(kf0, qf[0], st[mi], 0, 0, 0);
                st[mi] = __builtin_amdgcn_mfma_f32_16x16x32_bf16(kf1, qf[1], st[mi], 0, 0, 0);
            }

            u16* vt = Vt[gb];
#pragma unroll
            for (int c4 = 0; c4 < 4; c4++) {
                const u16x4 vv = {vreg[c4 * 4], vreg[c4 * 4 + 1], vreg[c4 * 4 + 2], vreg[c4 * 4 + 3]};
                *(u16x4*)&vt[vhd * VT_STR + vkb * 16 + c4 * 4] = vv;
            }
            __syncthreads();

            float pmax = -1e30f;
#pragma unroll
            for (int mi = 0; mi < 4; mi++)
#pragma unroll
                for (int r = 0; r < 4; r++) {
                    float sv = st[mi][r] * SC;   // score in log2 domain
                    if (kt == qt && (mi * 16 + quad * 4 + r) > (w * 16 + l15)) sv = -1e30f;
                    st[mi][r] = sv;
                    pmax = fmaxf(pmax, sv);
                }
            pmax = fmaxf(pmax, __shfl_xor(pmax, 16, 64));
            pmax = fmaxf(pmax, __shfl_xor(pmax, 32, 64));
            const float mnew = fmaxf(m_i, pmax);
            const float alpha = __builtin_amdgcn_exp2f(m_i - mnew);
            m_i = mnew;

            float psum = 0.f;
#pragma unroll
            for (int mi = 0; mi < 4; mi++) {
                float p[4];
#pragma unroll
                for (int r = 0; r < 4; r++) {
                    p[r] = __builtin_amdgcn_exp2f(st[mi][r] - mnew);
                    psum += p[r];
                }
                const u32x2 pk2 = {pack2(p[0], p[1]), pack2(p[2], p[3])};
                *(u32x2*)&myPt[l15 * VT_STR + mi * 16 + quad * 4] = pk2;
            }
            psum += __shfl_xor(psum, 16, 64);
            psum += __shfl_xor(psum, 32, 64);
            l_i = l_i * alpha + psum;

#pragma unroll
            for (int mi = 0; mi < 4; mi++) oacc[mi] *= alpha;

            bf16x8 pf[2];
            pf[0] = __builtin_bit_cast(bf16x8, *(const u16x8*)&myPt[l15 * VT_STR + quad * 8]);
            pf[1] = __builtin_bit_cast(bf16x8, *(const u16x8*)&myPt[l15 * VT_STR + 32 + quad * 8]);
#pragma unroll
            for (int mi = 0; mi < 4; mi++) {
                const bf16x8 vf0 = __builtin_bit_cast(bf16x8, *(const u16x8*)&vt[(mi * 16 + l15) * VT_STR + quad * 8]);
                const bf16x8 vf1 = __builtin_bit_cast(bf16x8, *(const u16x8*)&vt[(mi * 16 + l15) * VT_STR + 32 + quad * 8]);
                oacc[mi] = __builtin_amdgcn_mfma_f32_16x16x32_bf16(vf0, pf[0], oacc[mi], 0, 0, 0);
                oacc[mi] = __builtin_amdgcn_mfma_f32_16x16x32_bf16(vf1, pf[1], oacc[mi], 0, 0, 0);
            }
            gb ^= 1;
        }

        const float inv = 1.0f / l_i;
        const int b = bh >> 5, h = bh & 31;
        const int t = qt * 64 + w * 16 + l15;
        u16* cp = ctx + ((size_t)(b * T_ + t)) * C_ + h * HD_;
#pragma unroll
        for (int mi = 0; mi < 4; mi++) {
            const u16x4 ov = {f2b(oacc[mi][0] * inv), f2b(oacc[mi][1] * inv),
                              f2b(oacc[mi][2] * inv), f2b(oacc[mi][3] * inv)};
            *(u16x4*)(cp + mi * 16 + quad * 4) = ov;
        }
    }
}

extern "C" void kernel_launch(void* const* d_in, const int* in_sizes, int n_in,
                              void* d_out, int out_size, void* d_ws, size_t ws_size,
                              hipStream_t stream) {
    const float* x      = (const float*)d_in[0];
    const float* rope   = (const float*)d_in[3];
    const float* Wqkv_w = (const float*)d_in[4];
    const float* Wqkv_b = (const float*)d_in[5];
    const float* out_w  = (const float*)d_in[6];
    const float* out_b  = (const float*)d_in[7];
    float* out = (float*)d_out;

    // ws layout (u16 elems), total 100.7 MB:
    //   xb 8.39M | wqkvb 12.58M | outwb 4.19M | qT 8.39M | kT 8.39M | vT 8.39M
    //   ctx aliases xb (x dead after gemm0)
    const size_t headElems = (size_t)B_ * H_ * T_ * HD_;     // 8388608
    u16* xb    = (u16*)d_ws;
    u16* wqkvb = xb + headElems;
    u16* outwb = wqkvb + 12582912;
    u16* qTp   = outwb + 4194304;
    u16* kTp   = qTp + headElems;
    u16* vTp   = kTp + headElems;
    u16* ctx   = xb;

    convert_bf16<<<dim3(2048), 256, 0, stream>>>(x, xb, 2097152);
    convert_bf16<<<dim3(3072), 256, 0, stream>>>(Wqkv_w, wqkvb, 3145728);
    convert_bf16<<<dim3(1024), 256, 0, stream>>>(out_w, outwb, 1048576);

    gemm256_qkv<<<dim3(24, 16), 512, 0, stream>>>(xb, wqkvb, Wqkv_b, rope, qTp, kTp, vTp);
    attn_mfma<<<dim3(8, 128), 256, 0, stream>>>(qTp, kTp, vTp, ctx);
    gemm_bt<1><<<dim3(16, 32), 256, 0, stream>>>(ctx, outwb, out_b, rope, out, nullptr, nullptr);
}

// Round 4
// 445.284 us; speedup vs baseline: 1.0425x; 1.0425x over previous
//
#include <hip/hip_runtime.h>

typedef unsigned short u16;
typedef unsigned int u32;
typedef __bf16 bf16x8 __attribute__((ext_vector_type(8)));
typedef float floatx4 __attribute__((ext_vector_type(4)));
typedef u16 u16x4 __attribute__((ext_vector_type(4)));
typedef u16 u16x8 __attribute__((ext_vector_type(8)));
typedef u32 u32x2 __attribute__((ext_vector_type(2)));

#define B_ 4
#define T_ 1024
#define C_ 2048
#define H_ 32
#define HD_ 64

__device__ __forceinline__ float b2f(u16 u) {
    u32 x = ((u32)u) << 16;
    return __builtin_bit_cast(float, x);
}
__device__ __forceinline__ u16 f2b(float f) {          // RNE (epilogues)
    u32 i = __builtin_bit_cast(u32, f);
    u32 r = (i + 0x7FFFu + ((i >> 16) & 1u)) >> 16;
    return (u16)r;
}
// pack two fp32 -> two bf16 (round-half-up), 2 adds + 1 v_perm_b32
__device__ __forceinline__ u32 pack2(float a, float b) {
    const u32 ua = __builtin_bit_cast(u32, a) + 0x8000u;
    const u32 ub = __builtin_bit_cast(u32, b) + 0x8000u;
    return __builtin_amdgcn_perm(ub, ua, 0x07060302u);  // [ub_hi : ua_hi]
}

#define GLOAD16(gp, lp) __builtin_amdgcn_global_load_lds( \
    (const __attribute__((address_space(1))) void*)(gp),  \
    (__attribute__((address_space(3))) void*)(lp), 16, 0, 0)

// ---------------------------------------------------------------------------
// fused fp32 -> bf16 convert for x | Wqkv_w | out_w. The three bf16
// destinations are contiguous in ws (xb | wqkvb | outwb), so dst indexing is
// uniform; only the source base/offset branches. One kernel instead of three
// removes two launch gaps.
// ---------------------------------------------------------------------------
__global__ __launch_bounds__(256) void convert_all(const float* __restrict__ x,
                                                   const float* __restrict__ wqkv,
                                                   const float* __restrict__ outw,
                                                   u16* __restrict__ dst) {
    const int stride = gridDim.x * 256;
    for (int i = blockIdx.x * 256 + threadIdx.x; i < 6291456; i += stride) {
        const float* s;
        int off;
        if (i < 2097152) { s = x; off = i; }
        else if (i < 5242880) { s = wqkv; off = i - 2097152; }
        else { s = outw; off = i - 5242880; }
        const floatx4 v = *(const floatx4*)(s + (size_t)off * 4);
        const u32x2 h = {pack2(v.x, v.y), pack2(v.z, v.w)};
        *(u32x2*)(dst + (size_t)i * 4) = h;
    }
}

// ---------------------------------------------------------------------------
// GEMM: C[m,n] = sum_k A[m,k] * W[n,k] + bias[n]   (A, W bf16 row-major)
// m97 structure + XOR-swizzled LDS (verified 828 TF on the QKV shape; the
// 256^2 8-phase attempt measured SLOWER here: 384 blocks at 1 block/CU has a
// 75% tail cap and resident MfmaUtil didn't beat 37% -- reverted).
// MODE 0: epilogue bias + RoPE + scatter to q/k/v (B,H,T,hd) bf16.
// MODE 1: epilogue bias, fp32 row-major store.
// ---------------------------------------------------------------------------
template <int MODE>
__global__ __launch_bounds__(256) void gemm_bt(const u16* __restrict__ A,
                                               const u16* __restrict__ W,
                                               const float* __restrict__ bias,
                                               const float* __restrict__ rope,
                                               void* __restrict__ o0v,
                                               u16* __restrict__ o1,
                                               u16* __restrict__ o2) {
    const int Kdim = 2048;
    __shared__ __align__(16) u16 As[128 * 64];
    __shared__ __align__(16) u16 Bs[128 * 64];

    const int tid = threadIdx.x;
    const int w = tid >> 6, lane = tid & 63;
    const int wr = w >> 1, wc = w & 1;
    const int quad = lane >> 4, l15 = lane & 15;
    const int mBase = blockIdx.y * 128, nBase = blockIdx.x * 128;

    floatx4 acc[4][4] = {};

    // swizzled staging: local row lrow, fetch col-block (lane&7)^lrow
    const int lrow = lane >> 3;
    const int lcol = ((lane & 7) ^ lrow) * 8;
    const u16* Ap = A + (size_t)(mBase + lrow) * Kdim + lcol;
    const u16* Wp = W + (size_t)(nBase + lrow) * Kdim + lcol;

    const int xk = l15 & 7;   // read-side XOR key (row & 7)

    for (int k0 = 0; k0 < Kdim; k0 += 64) {
#pragma unroll
        for (int i = 0; i < 4; i++) {
            const int c = i * 4 + w;
            GLOAD16(Ap + (size_t)c * 8 * Kdim + k0, &As[c * 512]);
            GLOAD16(Wp + (size_t)c * 8 * Kdim + k0, &Bs[c * 512]);
        }
        __syncthreads();
#pragma unroll
        for (int ks = 0; ks < 64; ks += 32) {
            bf16x8 af[4], bfr[4];
#pragma unroll
            for (int i = 0; i < 4; i++) {
                const int co = (((ks >> 3) + quad) ^ xk) * 8;
                af[i] = *(const bf16x8*)&As[(wr * 64 + i * 16 + l15) * 64 + co];
            }
#pragma unroll
            for (int j = 0; j < 4; j++) {
                const int co = (((ks >> 3) + quad) ^ xk) * 8;
                bfr[j] = *(const bf16x8*)&Bs[(wc * 64 + j * 16 + l15) * 64 + co];
            }
#pragma unroll
            for (int i = 0; i < 4; i++)
#pragma unroll
                for (int j = 0; j < 4; j++)
                    acc[i][j] = __builtin_amdgcn_mfma_f32_16x16x32_bf16(af[i], bfr[j], acc[i][j], 0, 0, 0);
        }
        __syncthreads();
    }

    // epilogue: C/D layout col = lane&15 (per j-frag), row = quad*4 + reg (per i-frag)
    const int nq = nBase + wc * 64;
    float bv[4];
#pragma unroll
    for (int j = 0; j < 4; j++) bv[j] = bias[nq + j * 16 + l15];

    if (MODE == 0) {
        const int region = nq >> 11;            // 0=q 1=k 2=v (tile never straddles)
        const int h = (nq & 2047) >> 6;
        const int d = l15;
        u16* dst = (region == 0) ? (u16*)o0v : ((region == 1) ? o1 : o2);
#pragma unroll
        for (int i = 0; i < 4; i++) {
#pragma unroll
            for (int r = 0; r < 4; r++) {
                const int m = mBase + wr * 64 + i * 16 + quad * 4 + r;
                const int b = m >> 10, t = m & 1023;
                float v0 = acc[i][0][r] + bv[0];
                float v1 = acc[i][1][r] + bv[1];
                float v2 = acc[i][2][r] + bv[2];
                float v3 = acc[i][3][r] + bv[3];
                const size_t base = ((size_t)(b * H_ + h) * T_ + t) * HD_;
                if (region < 2) {
                    const float cz = rope[t * 32 + d * 2];
                    const float sz = rope[t * 32 + d * 2 + 1];
                    const float n0 = v0 * cz - v1 * sz;
                    const float n1 = v1 * cz + v0 * sz;
                    dst[base + d] = f2b(n0);
                    dst[base + 16 + d] = f2b(n1);
                } else {
                    dst[base + d] = f2b(v0);
                    dst[base + 16 + d] = f2b(v1);
                }
                dst[base + 32 + d] = f2b(v2);
                dst[base + 48 + d] = f2b(v3);
            }
        }
    } else {
        float* outf = (float*)o0v;
#pragma unroll
        for (int i = 0; i < 4; i++)
#pragma unroll
            for (int r = 0; r < 4; r++) {
                const int m = mBase + wr * 64 + i * 16 + quad * 4 + r;
                const size_t o = (size_t)m * 2048 + nq;
#pragma unroll
                for (int j = 0; j < 4; j++)
                    outf[o + j * 16 + l15] = acc[i][j][r] + bv[j];
            }
    }
}

// ---------------------------------------------------------------------------
// MFMA flash attention, KVBLK=128.
// Balanced pairs {x, 15-x} per block (round-1, verified). This round: two
// 64-key tiles share ONE online-softmax pass -> per-key cost of the
// shfl-reduce rounds, alpha/exp chain, oacc rescale, and loop control is
// halved (the latency-bound serial overhead). Barrier count per key is
// unchanged (2 per 128 vs 1 per 64). Uniform predicate v1 skips the dead
// half on even-qt last iterations (skipped halves also skip PV, so stale
// LDS is never multiplied in). LDS 34.8 KB -> still 4 blocks/CU.
// ---------------------------------------------------------------------------
#define VT_STR 136   // 128 keys + 8 pad; row stride 272B: 16B-aligned, mod-4-dword banks (same as proven 72)

__global__ __launch_bounds__(256) void attn_mfma(const u16* __restrict__ qT,
                                                 const u16* __restrict__ kT,
                                                 const u16* __restrict__ vT,
                                                 u16* __restrict__ ctx) {
    __shared__ __align__(16) u16 Vt[64 * VT_STR];        // V^T: [hd][key 0..127]
    __shared__ __align__(16) u16 Pt[4 * 16 * VT_STR];    // per-wave P^T: [q][key 0..127]

    const int tid = threadIdx.x;
    const int w = tid >> 6, lane = tid & 63;
    const int quad = lane >> 4, l15 = lane & 15;
    const int bh = blockIdx.y;
    const size_t headBase = (size_t)bh * (T_ * HD_);

    u16* myPt = &Pt[w * 16 * VT_STR];
    const int vhd = tid & 63, vkb = tid >> 6;
    const float SC = 0.18033688011112042f;   // 0.125 * log2(e)

#pragma unroll 1
    for (int ti = 0; ti < 2; ti++) {
        const int qt = ti ? (15 - (int)blockIdx.x) : (int)blockIdx.x;
        const int qtb = qt * 64;
        const int qrow = w * 16 + l15;

        bf16x8 qf[2];
        {
            const u16* qr = qT + headBase + (size_t)(qtb + qrow) * HD_ + quad * 8;
            qf[0] = __builtin_bit_cast(bf16x8, *(const u16x8*)(qr));
            qf[1] = __builtin_bit_cast(bf16x8, *(const u16x8*)(qr + 32));
        }

        float m_i = -1e30f, l_i = 0.f;
        floatx4 oacc[4] = {};
        const int niter = (qt + 2) >> 1;

#pragma unroll 1
        for (int kt = 0; kt < niter; kt++) {
            const int kb0 = kt * 128;
            const int v1 = (kb0 + 64 <= qtb);     // second half valid?
            const u16* kp = kT + headBase + (size_t)kb0 * HD_;
            const u16* vp = vT + headBase + (size_t)kb0 * HD_;

            floatx4 st[8];

            // ---- half 0: V gather + QK^T (pre-barrier; no LDS writes) ----
            u16 vreg[16];
#pragma unroll
            for (int c = 0; c < 16; c++)
                vreg[c] = vp[(vkb * 16 + c) * HD_ + vhd];

#pragma unroll
            for (int mi = 0; mi < 4; mi++) {
                st[mi] = floatx4{};
                const u16* krow = kp + (mi * 16 + l15) * HD_ + quad * 8;
                const bf16x8 kf0 = __builtin_bit_cast(bf16x8, *(const u16x8*)(krow));
                const bf16x8 kf1 = __builtin_bit_cast(bf16x8, *(const u16x8*)(krow + 32));
                st[mi] = __builtin_amdgcn_mfma_f32_16x16x32_bf16(kf0, qf[0], st[mi], 0, 0, 0);
                st[mi] = __builtin_amdgcn_mfma_f32_16x16x32_bf16(kf1, qf[1], st[mi], 0, 0, 0);
            }

            __syncthreads();   // barrier A: previous iteration's PV reads done

#pragma unroll
            for (int c4 = 0; c4 < 4; c4++) {
                const u16x4 vv = {vreg[c4 * 4], vreg[c4 * 4 + 1], vreg[c4 * 4 + 2], vreg[c4 * 4 + 3]};
                *(u16x4*)&Vt[vhd * VT_STR + vkb * 16 + c4 * 4] = vv;
            }

            if (v1) {
                // ---- half 1: gather + QK^T + V write ----
#pragma unroll
                for (int c = 0; c < 16; c++)
                    vreg[c] = vp[(64 + vkb * 16 + c) * HD_ + vhd];
#pragma unroll
                for (int mi = 0; mi < 4; mi++) {
                    st[4 + mi] = floatx4{};
                    const u16* krow = kp + (64 + mi * 16 + l15) * HD_ + quad * 8;
                    const bf16x8 kf0 = __builtin_bit_cast(bf16x8, *(const u16x8*)(krow));
                    const bf16x8 kf1 = __builtin_bit_cast(bf16x8, *(const u16x8*)(krow + 32));
                    st[4 + mi] = __builtin_amdgcn_mfma_f32_16x16x32_bf16(kf0, qf[0], st[4 + mi], 0, 0, 0);
                    st[4 + mi] = __builtin_amdgcn_mfma_f32_16x16x32_bf16(kf1, qf[1], st[4 + mi], 0, 0, 0);
                }
#pragma unroll
                for (int c4 = 0; c4 < 4; c4++) {
                    const u16x4 vv = {vreg[c4 * 4], vreg[c4 * 4 + 1], vreg[c4 * 4 + 2], vreg[c4 * 4 + 3]};
                    *(u16x4*)&Vt[vhd * VT_STR + 64 + vkb * 16 + c4 * 4] = vv;
                }
            }

            __syncthreads();   // barrier B: Vt ready

            const int nmi = v1 ? 8 : 4;

            // ---- one softmax pass over up to 128 keys ----
            float pmax = -1e30f;
#pragma unroll
            for (int s = 0; s < 8; s++) {
                if (s >= nmi) break;
                const int hb = kb0 + (s >> 2) * 64;         // this half's base key
                const int diag = (hb == qtb);
#pragma unroll
                for (int r = 0; r < 4; r++) {
                    float sv = st[s][r] * SC;               // log2-domain score
                    if (diag && ((s & 3) * 16 + quad * 4 + r) > qrow) sv = -1e30f;
                    st[s][r] = sv;
                    pmax = fmaxf(pmax, sv);
                }
            }
            pmax = fmaxf(pmax, __shfl_xor(pmax, 16, 64));
            pmax = fmaxf(pmax, __shfl_xor(pmax, 32, 64));
            const float mnew = fmaxf(m_i, pmax);
            const float alpha = __builtin_amdgcn_exp2f(m_i - mnew);
            m_i = mnew;

            float psum = 0.f;
#pragma unroll
            for (int s = 0; s < 8; s++) {
                if (s >= nmi) break;
                float p[4];
#pragma unroll
                for (int r = 0; r < 4; r++) {
                    p[r] = __builtin_amdgcn_exp2f(st[s][r] - mnew);
                    psum += p[r];
                }
                const u32x2 pk2 = {pack2(p[0], p[1]), pack2(p[2], p[3])};
                *(u32x2*)&myPt[l15 * VT_STR + s * 16 + quad * 4] = pk2;
            }
            psum += __shfl_xor(psum, 16, 64);
            psum += __shfl_xor(psum, 32, 64);
            l_i = l_i * alpha + psum;

#pragma unroll
            for (int mi = 0; mi < 4; mi++) oacc[mi] *= alpha;

            // ---- PV over valid key-slots only (skipped slots never touch Vt) ----
            const int nks = v1 ? 4 : 2;
#pragma unroll
            for (int ks = 0; ks < 4; ks++) {
                if (ks >= nks) break;
                const bf16x8 pf = __builtin_bit_cast(bf16x8, *(const u16x8*)&myPt[l15 * VT_STR + ks * 32 + quad * 8]);
#pragma unroll
                for (int mi = 0; mi < 4; mi++) {
                    const bf16x8 vf = __builtin_bit_cast(bf16x8, *(const u16x8*)&Vt[(mi * 16 + l15) * VT_STR + ks * 32 + quad * 8]);
                    oacc[mi] = __builtin_amdgcn_mfma_f32_16x16x32_bf16(vf, pf, oacc[mi], 0, 0, 0);
                }
            }
        }

        const float inv = 1.0f / l_i;
        const int b = bh >> 5, h = bh & 31;
        const int t = qtb + qrow;
        u16* cp = ctx + ((size_t)(b * T_ + t)) * C_ + h * HD_;
#pragma unroll
        for (int mi = 0; mi < 4; mi++) {
            const u16x4 ov = {f2b(oacc[mi][0] * inv), f2b(oacc[mi][1] * inv),
                              f2b(oacc[mi][2] * inv), f2b(oacc[mi][3] * inv)};
            *(u16x4*)(cp + mi * 16 + quad * 4) = ov;
        }
    }
}

extern "C" void kernel_launch(void* const* d_in, const int* in_sizes, int n_in,
                              void* d_out, int out_size, void* d_ws, size_t ws_size,
                              hipStream_t stream) {
    const float* x      = (const float*)d_in[0];
    const float* rope   = (const float*)d_in[3];
    const float* Wqkv_w = (const float*)d_in[4];
    const float* Wqkv_b = (const float*)d_in[5];
    const float* out_w  = (const float*)d_in[6];
    const float* out_b  = (const float*)d_in[7];
    float* out = (float*)d_out;

    // ws layout (u16 elems), total 100.7 MB:
    //   xb 8.39M | wqkvb 12.58M | outwb 4.19M | qT 8.39M | kT 8.39M | vT 8.39M
    //   xb|wqkvb|outwb contiguous (fused convert); ctx aliases xb (x dead after gemm0)
    const size_t headElems = (size_t)B_ * H_ * T_ * HD_;     // 8388608
    u16* xb    = (u16*)d_ws;
    u16* wqkvb = xb + headElems;
    u16* outwb = wqkvb + 12582912;
    u16* qTp   = outwb + 4194304;
    u16* kTp   = qTp + headElems;
    u16* vTp   = kTp + headElems;
    u16* ctx   = xb;

    convert_all<<<dim3(3072), 256, 0, stream>>>(x, Wqkv_w, out_w, xb);

    gemm_bt<0><<<dim3(48, 32), 256, 0, stream>>>(xb, wqkvb, Wqkv_b, rope, qTp, kTp, vTp);
    attn_mfma<<<dim3(8, 128), 256, 0, stream>>>(qTp, kTp, vTp, ctx);
    gemm_bt<1><<<dim3(16, 32), 256, 0, stream>>>(ctx, outwb, out_b, rope, out, nullptr, nullptr);
}